// Round 14
// baseline (181.928 us; speedup 1.0000x reference)
//
#include <hip/hip_runtime.h>
#include <math.h>

#define N_NODES 50000
#define N_EDGES 800000
#define IN_DIM 128
#define OUT_DIM 16
#define N_HEADS 4
#define HID 64            // N_HEADS*OUT_DIM
#define AW_COLS 33        // 2*OUT_DIM+1
#define GN 16             // nodes per tile; 3125*16 = 50000 exact
#define GEMM_BLK ((N_NODES + GN - 1) / GN)             // 3125 tiles, x2 halves
#define HE 2              // edges per thread (hist) -- R35: was 16
#define HBLK ((N_EDGES + 256 * HE - 1) / (256 * HE))   // 1563
#define MAXDEG 64         // padded bucket width; deg~Poisson(16), max~35 (12 sigma margin)

// R35 = R33 fused form + ONE change: hist re-tiled HE 16->2 (196 -> 1563
// blocks). R34's decomposition finally measured the phases: hist_scatter was
// 48-57us at Occupancy 6%, VALUBusy 0.5% -- 196 blocks of 16 serially
// dependent atomic chains (atomicAdd ~500cy -> rank -> scatter -> next) was
// THE hidden monster all along; gemm_only and node_fused are both <48us.
// 8x more hist blocks = 8x concurrent chains; co-scheduled with gemm blocks
// the latency hides under gemm compute. Contention benign (~16 incr/addr).
// Numerics: every edge processed once; ranks permute -> node_fused accumulate
// order reorders within the f32 class already validated (R25/R33 passed with
// identical absmax); near-one-hot ev => sum order immaterial; max is
// order-independent.
// Ledger: R33 f32 GEMM passed, absmax identical -- f32 kept. R31 output-split
// kept (LDS 24576, 6 blk/CU). R29 f64 MFMA SHELVED (wrong lane mapping).
// R27 W-from-global loses. R26 launch_bounds spill. R24 more-waves-same-
// traffic loses. R23 dense accumulate loses (near-one-hot).

// LDS plan (= R33): phase1 sWh 16KB @0 + sN 8KB @16384 = 24576 B.
// phase2 overlay: scrF 9216 B @0, h_lds 2048 B @9216.
#define SMEM_DOUBLES 3072                  // 24576 B
#define SCR_OFF_F 2304                     // floats; h_lds at byte 9216

__global__ __launch_bounds__(256, 4) void gemm_hist(
    const float* __restrict__ nodes, const float* __restrict__ W,
    const float* __restrict__ b, const float* __restrict__ attn_W,
    const float* __restrict__ attn_b, const float* __restrict__ edges,
    float* __restrict__ h, double* __restrict__ z_src, double* __restrict__ z_dst,
    const int* __restrict__ senders, const int* __restrict__ receivers,
    int* __restrict__ counts, int* __restrict__ srt_padded,
    double* __restrict__ Ssum) {
    __shared__ double smem_d[SMEM_DOUBLES];    // 24576 B, multi-phase overlay
    float* sWh = (float*)smem_d;               // 16 KB: 32 W rows, rotated
    float* sN = (float*)(smem_d + 2048);       // 8 KB @byte 16384, rotated
    int t = threadIdx.x;

    if (blockIdx.x < HBLK) {
        // ---- hist + direct bucket-scatter: HE=2, 1563 blocks (R35) ----
        double* red = smem_d;
        int base = blockIdx.x * 256 * HE + t;
        double sp = 0.0;
        #pragma unroll
        for (int j = 0; j < HE; ++j) {
            int e = base + j * 256;
            if (e < N_EDGES) {
                int r = receivers[e];
                int rank = atomicAdd(&counts[r], 1);            // 0..deg-1
                if (rank < MAXDEG)
                    srt_padded[r * MAXDEG + rank] = senders[e];
                sp += (double)edges[senders[e]];
            }
        }
        red[t] = sp;
        __syncthreads();
        for (int off = 128; off > 0; off >>= 1) {
            if (t < off) red[t] += red[t + off];
            __syncthreads();
        }
        if (t == 0) atomicAdd(Ssum, red[0]);
    } else {
        // ---- gemm: one 32-out half of a 16-node tile; 4-way k-split; f32 ----
        int bidp = blockIdx.x - HBLK;          // [0, 6250)
        int hhalf = bidp & 1;                  // output half: 0 -> outs[0,32), 1 -> [32,64)
        int node0 = (bidp >> 1) * GN;

        for (int i4 = t; i4 < 32 * IN_DIM / 4; i4 += 256) {    // 1024 quads
            int o = i4 >> 5, kq = i4 & 31;     // o = local out row [0,32)
            float4 v = ((const float4*)W)[(hhalf * 32 + o) * (IN_DIM / 4) + kq];
            *(float4*)&sWh[o * IN_DIM + (((kq + o) & 31) << 2)] = v;
        }
        for (int i4 = t; i4 < GN * IN_DIM / 4; i4 += 256) {    // 512 quads, rotated
            int ln = i4 >> 5, kq = i4 & 31;
            float4 v = ((const float4*)nodes)[(long long)(node0 + ln) * (IN_DIM / 4) + kq];
            *(float4*)&sN[ln * IN_DIM + (((kq + ln) & 31) << 2)] = v;
        }
        __syncthreads();                   // barrier 1

        int w = t >> 6, l = t & 63;
        int og = l & 15;                   // local outs og + 16j, j=0..1
        int ng = l >> 4;                   // nodes   ng + 4i,  i=0..3
        int kbase = w * 8;                 // this wave's kq range [kbase, kbase+8)

        float acc[2][4];                   // [j][i] -- f32 accumulate
        #pragma unroll
        for (int j = 0; j < 2; ++j)
            #pragma unroll
            for (int i = 0; i < 4; ++i) acc[j][i] = 0.f;

        #pragma unroll
        for (int s = 0; s < 8; ++s) {
            int kq = kbase + s;
            float4 wq[2], xq[4];
            #pragma unroll
            for (int j = 0; j < 2; ++j) {
                int o = og + 16 * j;
                wq[j] = *(const float4*)&sWh[o * IN_DIM + (((kq + o) & 31) << 2)];
            }
            #pragma unroll
            for (int i = 0; i < 4; ++i) {
                int n = ng + 4 * i;
                xq[i] = *(const float4*)&sN[n * IN_DIM + (((kq + n) & 31) << 2)];
            }
            #pragma unroll
            for (int j = 0; j < 2; ++j) {
                #pragma unroll
                for (int i = 0; i < 4; ++i) {
                    acc[j][i] = fmaf(wq[j].x, xq[i].x, acc[j][i]);
                    acc[j][i] = fmaf(wq[j].y, xq[i].y, acc[j][i]);
                    acc[j][i] = fmaf(wq[j].z, xq[i].z, acc[j][i]);
                    acc[j][i] = fmaf(wq[j].w, xq[i].w, acc[j][i]);
                }
            }
        }
        __syncthreads();                   // barrier 2: sWh/sN reads done

        // ---- k-reduction (f32): all waves dump; waves 0,1 sum quad j=w ----
        float* scrF = (float*)smem_d;      // overlays dead staging; 9216 B
        float* h_lds = (float*)smem_d + SCR_OFF_F;     // 2 KB @byte 9216
        {
            float* dst = &scrF[(w * 64 + l) * 9];
            #pragma unroll
            for (int j = 0; j < 2; ++j)
                #pragma unroll
                for (int i = 0; i < 4; ++i) dst[j * 4 + i] = acc[j][i];
        }
        __syncthreads();                   // barrier 3
        if (w < 2) {
            int jw = w;                    // finalize local outs og + 16w
            #pragma unroll
            for (int i = 0; i < 4; ++i) {
                float sum = b[hhalf * 32 + og + 16 * jw];
                sum += scrF[(0 * 64 + l) * 9 + jw * 4 + i];   // k[0,32)
                sum += scrF[(1 * 64 + l) * 9 + jw * 4 + i];   // k[32,64)
                sum += scrF[(2 * 64 + l) * 9 + jw * 4 + i];   // k[64,96)
                sum += scrF[(3 * 64 + l) * 9 + jw * 4 + i];   // k[96,128)
                h_lds[(ng + 4 * i) * 32 + og + 16 * jw] = sum;
            }
        }
        __syncthreads();                   // barrier 4

        // ---- epilogue: heads {hhalf*2, hhalf*2+1}; f64 chains verbatim ----
        int half = l >> 5;
        int o2 = l & 31;                   // local out column [0,32)
        int nwbase = w * 4 + half * 2;
        int hdl = o2 >> 4, d = o2 & 15;
        int hdg = hhalf * 2 + hdl;         // global head
        double aw0 = (double)attn_W[hdg * AW_COLS + d];            // a_src
        double aw1 = (double)attn_W[hdg * AW_COLS + OUT_DIM + d];  // a_dst
        double wE = (double)attn_W[hdg * AW_COLS + 2 * OUT_DIM];
        double bbv = (double)attn_b[hdg];
        #pragma unroll
        for (int j = 0; j < 2; ++j) {
            int nl = nwbase + j;
            int n = node0 + nl;            // always < 50000 (exact tiling)
            float hf = h_lds[nl * 32 + o2];
            double c0 = (double)hf * aw0;
            double c1 = (double)hf * aw1;
            #pragma unroll
            for (int k = 1; k <= 8; k <<= 1) {
                c0 += __shfl_xor(c0, k, 64);
                c1 += __shfl_xor(c1, k, 64);
            }
            if (d == 0) {
                double se = (double)edges[n];
                z_src[n * N_HEADS + hdg] = c0 + se * wE;
                z_dst[n * N_HEADS + hdg] = c1 + bbv;
            }
        }
        // h write: this block's half-columns for 16 nodes (128 float4)
        if (t < 128) {
            int node = t >> 3, c = t & 7;
            ((float4*)h)[(long long)(node0 + node) * (HID / 4) + hhalf * 8 + c] =
                ((const float4*)h_lds)[node * 8 + c];
        }
    }
}

// R22 form (best known, FROZEN). TWO nodes per wave, phases pairwise
// interleaved; near-one-hot softmax -> ballot loop does ~1-4 gathers/node
// (R23's dense rewrite did 16x traffic, +12us -- don't retry).
__global__ __launch_bounds__(256, 8) void node_fused(
    const float* __restrict__ h, const double* __restrict__ z_src,
    const double* __restrict__ z_dst,
    const int* __restrict__ srt_padded, const int* __restrict__ counts,
    const double* __restrict__ Ssum, float* __restrict__ out) {
    int w = threadIdx.x >> 6;
    int lane = threadIdx.x & 63;
    int nA = blockIdx.x * 8 + w * 2;     // grid exact: 6250*8 = 50000
    int nB = nA + 1;
    int hd = lane >> 4, q = lane & 15;

    int degA = counts[nA]; if (degA > MAXDEG) degA = MAXDEG;
    int degB = counts[nB]; if (degB > MAXDEG) degB = MAXDEG;
    double S = 4.0 * Ssum[0];                       // sent_e tiled over heads
    double zdA = z_dst[nA * N_HEADS + hd];
    double zdB = z_dst[nB * N_HEADS + hd];

    // ---- edge-id gather (both nodes issued before use) ----
    int sA[4], sB[4];
    #pragma unroll
    for (int j = 0; j < 4; ++j) {
        int ei = q + 16 * j;
        sA[j] = (ei < degA) ? srt_padded[nA * MAXDEG + ei] : 0;
        sB[j] = (ei < degB) ? srt_padded[nB * MAXDEG + ei] : 0;
    }
    // ---- z_src scatter-gather + leaky (f64, then round) ----
    float yA[4], yB[4];
    #pragma unroll
    for (int j = 0; j < 4; ++j) {
        int ei = q + 16 * j;
        yA[j] = -INFINITY;
        yB[j] = -INFINITY;
        if (ei < degA) {
            double yy = z_src[sA[j] * N_HEADS + hd] + zdA;
            yy = yy > 0.0 ? yy : 0.01 * yy;
            yA[j] = (float)yy;
        }
        if (ei < degB) {
            double yy = z_src[sB[j] * N_HEADS + hd] + zdB;
            yy = yy > 0.0 ? yy : 0.01 * yy;
            yB[j] = (float)yy;
        }
    }
    // ---- per-head max: two butterfly chains interleaved ----
    float mA = fmaxf(fmaxf(yA[0], yA[1]), fmaxf(yA[2], yA[3]));
    float mB = fmaxf(fmaxf(yB[0], yB[1]), fmaxf(yB[2], yB[3]));
    #pragma unroll
    for (int k = 1; k <= 8; k <<= 1) {
        mA = fmaxf(mA, __shfl_xor(mA, k, 64));
        mB = fmaxf(mB, __shfl_xor(mB, k, 64));
    }
    // ---- exp + denominator (same expression order as R21) ----
    float evA[4], evB[4];
    float dA = 0.f, dB = 0.f;
    #pragma unroll
    for (int j = 0; j < 4; ++j) {
        evA[j] = (yA[j] == -INFINITY) ? 0.f
               : __expf((float)(S * ((double)yA[j] - (double)mA)));
        dA += evA[j];
        evB[j] = (yB[j] == -INFINITY) ? 0.f
               : __expf((float)(S * ((double)yB[j] - (double)mB)));
        dB += evB[j];
    }
    #pragma unroll
    for (int k = 1; k <= 8; k <<= 1) {
        dA += __shfl_xor(dA, k, 64);
        dB += __shfl_xor(dB, k, 64);
    }
    // ---- ballot-compressed accumulate, node A then node B (order preserved) ----
    float accA = 0.f;
    #pragma unroll
    for (int j = 0; j < 4; ++j) {
        unsigned long long mk = __ballot(evA[j] != 0.f);
        unsigned um = (unsigned)((mk | (mk >> 16) | (mk >> 32) | (mk >> 48)) & 0xFFFFull);
        while (um) {
            int qq = __builtin_ctz(um);
            um &= um - 1;
            int src = (lane & 48) | qq;                 // own head's copy
            float evv = __shfl(evA[j], src, 64);
            int sj = __shfl(sA[j], src, 64);
            if (evv != 0.f)
                accA = fmaf(evv, h[sj * HID + lane], accA);
        }
    }
    float accB = 0.f;
    #pragma unroll
    for (int j = 0; j < 4; ++j) {
        unsigned long long mk = __ballot(evB[j] != 0.f);
        unsigned um = (unsigned)((mk | (mk >> 16) | (mk >> 32) | (mk >> 48)) & 0xFFFFull);
        while (um) {
            int qq = __builtin_ctz(um);
            um &= um - 1;
            int src = (lane & 48) | qq;
            float evv = __shfl(evB[j], src, 64);
            int sj = __shfl(sB[j], src, 64);
            if (evv != 0.f)
                accB = fmaf(evv, h[sj * HID + lane], accB);
        }
    }
    float rA = (dA > 0.f) ? accA / dA : 0.f;
    float rB = (dB > 0.f) ? accB / dB : 0.f;
    out[nA * HID + lane] = rA > 0.f ? rA : 0.01f * rA;
    out[nB * HID + lane] = rB > 0.f ? rB : 0.01f * rB;
}

static inline char* ws_take(char*& p, size_t bytes) {
    char* cur = p;
    p += (bytes + 255) & ~(size_t)255;   // keep every buffer 256B-aligned
    return cur;
}

extern "C" void kernel_launch(void* const* d_in, const int* in_sizes, int n_in,
                              void* d_out, int out_size, void* d_ws, size_t ws_size,
                              hipStream_t stream) {
    const float* nodes     = (const float*)d_in[0];
    const float* edges     = (const float*)d_in[1];
    const int*   senders   = (const int*)d_in[2];
    const int*   receivers = (const int*)d_in[3];
    const float* W         = (const float*)d_in[4];
    const float* b         = (const float*)d_in[5];
    const float* attn_W    = (const float*)d_in[6];
    const float* attn_b    = (const float*)d_in[7];
    float* out = (float*)d_out;

    char* p = (char*)d_ws;
    float*  h          = (float*)ws_take(p, sizeof(float) * N_NODES * HID);
    double* z_src      = (double*)ws_take(p, sizeof(double) * N_NODES * N_HEADS);
    double* z_dst      = (double*)ws_take(p, sizeof(double) * N_NODES * N_HEADS);
    int*    counts     = (int*)ws_take(p, sizeof(int) * N_NODES);   // contiguous with
    char*   zpad       = ws_take(p, 256);                           // Ssum: one memset
    double* Ssum       = (double*)zpad;
    int*    srt_padded = (int*)ws_take(p, sizeof(int) * (size_t)N_NODES * MAXDEG);

    // counts (256B-rounded) + the Ssum pad in one memset; srt_padded needs no init
    hipMemsetAsync(counts, 0, ((sizeof(int) * N_NODES + 255) & ~(size_t)255) + 256, stream);

    gemm_hist<<<HBLK + 2 * GEMM_BLK, 256, 0, stream>>>(
        nodes, W, b, attn_W, attn_b, edges, h, z_src, z_dst,
        senders, receivers, counts, srt_padded, Ssum);
    node_fused<<<(N_NODES + 7) / 8, 256, 0, stream>>>(
        h, z_src, z_dst, srt_padded, counts, Ssum, out);
}

// Round 15
// 169.323 us; speedup vs baseline: 1.0744x; 1.0744x over previous
//
#include <hip/hip_runtime.h>
#include <math.h>

#define N_NODES 50000
#define N_EDGES 800000
#define IN_DIM 128
#define OUT_DIM 16
#define N_HEADS 4
#define HID 64            // N_HEADS*OUT_DIM
#define AW_COLS 33        // 2*OUT_DIM+1
#define GN 16             // nodes per tile; 3125*16 = 50000 exact
#define GEMM_BLK ((N_NODES + GN - 1) / GN)             // 3125 tiles, x2 halves
#define HE 16             // edges per thread (hist) -- R36: back to 16 (R35's HE=2 regressed)
#define HBLK ((N_EDGES + 256 * HE - 1) / (256 * HE))   // 196
#define MAXDEG 64         // padded bucket width; deg~Poisson(16), max~35 (12 sigma margin)

// R36 = R33 anchor + ONE change: hist inner loop ILP-batched. R35 post-mortem:
// HE=2 (1563 blocks) regressed 65->90us -- scheduler flooded with latency-
// bound blocks, per-block reduction overhead amortized 8x worse. The real
// hist fix: the 16 atomicAdds per thread are INDEPENDENT; only program order
// (rank consumed immediately -> waitcnt per edge) serialized them. Batch by
// 8: issue 8 atomics back-to-back (8 outstanding), then 8 scatter writes,
// then 8 edge-gathers. Same block count/contention; per-thread exposed
// latency ~8x less. Batch=8 (not 16) caps extra VGPRs ~24 so kernel stays
// <=85 VGPR (6-blk/CU bound; R26 lesson pre-checked). Ranks permute -- same
// reorder class validated R25/R33/R35 (absmax identical each time).
// Ledger: R33 f32 GEMM kept (absmax identical to f64). R31 output-split kept.
// R34 decomposition: hist ~50us@6%occ / gemm_only <48 / node_fused <48.
// R35 HE=2 regressed (don't re-flood scheduler). R29 f64 MFMA SHELVED.
// R27 W-from-global loses. R26 launch_bounds spill. R24 more-waves-same-
// traffic loses. R23 dense accumulate loses (near-one-hot softmax).

// LDS plan (= R33): phase1 sWh 16KB @0 + sN 8KB @16384 = 24576 B.
// phase2 overlay: scrF 9216 B @0, h_lds 2048 B @9216.
#define SMEM_DOUBLES 3072                  // 24576 B
#define SCR_OFF_F 2304                     // floats; h_lds at byte 9216

__global__ __launch_bounds__(256, 4) void gemm_hist(
    const float* __restrict__ nodes, const float* __restrict__ W,
    const float* __restrict__ b, const float* __restrict__ attn_W,
    const float* __restrict__ attn_b, const float* __restrict__ edges,
    float* __restrict__ h, double* __restrict__ z_src, double* __restrict__ z_dst,
    const int* __restrict__ senders, const int* __restrict__ receivers,
    int* __restrict__ counts, int* __restrict__ srt_padded,
    double* __restrict__ Ssum) {
    __shared__ double smem_d[SMEM_DOUBLES];    // 24576 B, multi-phase overlay
    float* sWh = (float*)smem_d;               // 16 KB: 32 W rows, rotated
    float* sN = (float*)(smem_d + 2048);       // 8 KB @byte 16384, rotated
    int t = threadIdx.x;

    if (blockIdx.x < HBLK) {
        // ---- hist + bucket-scatter, ILP-batched by 8 (R36) ----
        double* red = smem_d;
        int base = blockIdx.x * 256 * HE + t;
        double sp = 0.0;
        #pragma unroll
        for (int h0 = 0; h0 < HE; h0 += 8) {
            int rr[8], ss[8], rk[8];
            #pragma unroll
            for (int j = 0; j < 8; ++j) {           // independent index loads
                int e = base + (h0 + j) * 256;
                bool v = (e < N_EDGES);
                rr[j] = v ? receivers[e] : -1;
                ss[j] = v ? senders[e] : 0;
            }
            #pragma unroll
            for (int j = 0; j < 8; ++j)             // 8 atomics in flight
                rk[j] = (rr[j] >= 0) ? atomicAdd(&counts[rr[j]], 1) : MAXDEG;
            #pragma unroll
            for (int j = 0; j < 8; ++j)             // independent scatters
                if (rr[j] >= 0 && rk[j] < MAXDEG)
                    srt_padded[rr[j] * MAXDEG + rk[j]] = ss[j];
            #pragma unroll
            for (int j = 0; j < 8; ++j)             // independent gathers
                if (rr[j] >= 0) sp += (double)edges[ss[j]];
        }
        red[t] = sp;
        __syncthreads();
        for (int off = 128; off > 0; off >>= 1) {
            if (t < off) red[t] += red[t + off];
            __syncthreads();
        }
        if (t == 0) atomicAdd(Ssum, red[0]);
    } else {
        // ---- gemm: one 32-out half of a 16-node tile; 4-way k-split; f32 ----
        int bidp = blockIdx.x - HBLK;          // [0, 6250)
        int hhalf = bidp & 1;                  // output half: 0 -> outs[0,32), 1 -> [32,64)
        int node0 = (bidp >> 1) * GN;

        for (int i4 = t; i4 < 32 * IN_DIM / 4; i4 += 256) {    // 1024 quads
            int o = i4 >> 5, kq = i4 & 31;     // o = local out row [0,32)
            float4 v = ((const float4*)W)[(hhalf * 32 + o) * (IN_DIM / 4) + kq];
            *(float4*)&sWh[o * IN_DIM + (((kq + o) & 31) << 2)] = v;
        }
        for (int i4 = t; i4 < GN * IN_DIM / 4; i4 += 256) {    // 512 quads, rotated
            int ln = i4 >> 5, kq = i4 & 31;
            float4 v = ((const float4*)nodes)[(long long)(node0 + ln) * (IN_DIM / 4) + kq];
            *(float4*)&sN[ln * IN_DIM + (((kq + ln) & 31) << 2)] = v;
        }
        __syncthreads();                   // barrier 1

        int w = t >> 6, l = t & 63;
        int og = l & 15;                   // local outs og + 16j, j=0..1
        int ng = l >> 4;                   // nodes   ng + 4i,  i=0..3
        int kbase = w * 8;                 // this wave's kq range [kbase, kbase+8)

        float acc[2][4];                   // [j][i] -- f32 accumulate
        #pragma unroll
        for (int j = 0; j < 2; ++j)
            #pragma unroll
            for (int i = 0; i < 4; ++i) acc[j][i] = 0.f;

        #pragma unroll
        for (int s = 0; s < 8; ++s) {
            int kq = kbase + s;
            float4 wq[2], xq[4];
            #pragma unroll
            for (int j = 0; j < 2; ++j) {
                int o = og + 16 * j;
                wq[j] = *(const float4*)&sWh[o * IN_DIM + (((kq + o) & 31) << 2)];
            }
            #pragma unroll
            for (int i = 0; i < 4; ++i) {
                int n = ng + 4 * i;
                xq[i] = *(const float4*)&sN[n * IN_DIM + (((kq + n) & 31) << 2)];
            }
            #pragma unroll
            for (int j = 0; j < 2; ++j) {
                #pragma unroll
                for (int i = 0; i < 4; ++i) {
                    acc[j][i] = fmaf(wq[j].x, xq[i].x, acc[j][i]);
                    acc[j][i] = fmaf(wq[j].y, xq[i].y, acc[j][i]);
                    acc[j][i] = fmaf(wq[j].z, xq[i].z, acc[j][i]);
                    acc[j][i] = fmaf(wq[j].w, xq[i].w, acc[j][i]);
                }
            }
        }
        __syncthreads();                   // barrier 2: sWh/sN reads done

        // ---- k-reduction (f32): all waves dump; waves 0,1 sum quad j=w ----
        float* scrF = (float*)smem_d;      // overlays dead staging; 9216 B
        float* h_lds = (float*)smem_d + SCR_OFF_F;     // 2 KB @byte 9216
        {
            float* dst = &scrF[(w * 64 + l) * 9];
            #pragma unroll
            for (int j = 0; j < 2; ++j)
                #pragma unroll
                for (int i = 0; i < 4; ++i) dst[j * 4 + i] = acc[j][i];
        }
        __syncthreads();                   // barrier 3
        if (w < 2) {
            int jw = w;                    // finalize local outs og + 16w
            #pragma unroll
            for (int i = 0; i < 4; ++i) {
                float sum = b[hhalf * 32 + og + 16 * jw];
                sum += scrF[(0 * 64 + l) * 9 + jw * 4 + i];   // k[0,32)
                sum += scrF[(1 * 64 + l) * 9 + jw * 4 + i];   // k[32,64)
                sum += scrF[(2 * 64 + l) * 9 + jw * 4 + i];   // k[64,96)
                sum += scrF[(3 * 64 + l) * 9 + jw * 4 + i];   // k[96,128)
                h_lds[(ng + 4 * i) * 32 + og + 16 * jw] = sum;
            }
        }
        __syncthreads();                   // barrier 4

        // ---- epilogue: heads {hhalf*2, hhalf*2+1}; f64 chains verbatim ----
        int half = l >> 5;
        int o2 = l & 31;                   // local out column [0,32)
        int nwbase = w * 4 + half * 2;
        int hdl = o2 >> 4, d = o2 & 15;
        int hdg = hhalf * 2 + hdl;         // global head
        double aw0 = (double)attn_W[hdg * AW_COLS + d];            // a_src
        double aw1 = (double)attn_W[hdg * AW_COLS + OUT_DIM + d];  // a_dst
        double wE = (double)attn_W[hdg * AW_COLS + 2 * OUT_DIM];
        double bbv = (double)attn_b[hdg];
        #pragma unroll
        for (int j = 0; j < 2; ++j) {
            int nl = nwbase + j;
            int n = node0 + nl;            // always < 50000 (exact tiling)
            float hf = h_lds[nl * 32 + o2];
            double c0 = (double)hf * aw0;
            double c1 = (double)hf * aw1;
            #pragma unroll
            for (int k = 1; k <= 8; k <<= 1) {
                c0 += __shfl_xor(c0, k, 64);
                c1 += __shfl_xor(c1, k, 64);
            }
            if (d == 0) {
                double se = (double)edges[n];
                z_src[n * N_HEADS + hdg] = c0 + se * wE;
                z_dst[n * N_HEADS + hdg] = c1 + bbv;
            }
        }
        // h write: this block's half-columns for 16 nodes (128 float4)
        if (t < 128) {
            int node = t >> 3, c = t & 7;
            ((float4*)h)[(long long)(node0 + node) * (HID / 4) + hhalf * 8 + c] =
                ((const float4*)h_lds)[node * 8 + c];
        }
    }
}

// R22 form (best known, FROZEN). TWO nodes per wave, phases pairwise
// interleaved; near-one-hot softmax -> ballot loop does ~1-4 gathers/node
// (R23's dense rewrite did 16x traffic, +12us -- don't retry).
__global__ __launch_bounds__(256, 8) void node_fused(
    const float* __restrict__ h, const double* __restrict__ z_src,
    const double* __restrict__ z_dst,
    const int* __restrict__ srt_padded, const int* __restrict__ counts,
    const double* __restrict__ Ssum, float* __restrict__ out) {
    int w = threadIdx.x >> 6;
    int lane = threadIdx.x & 63;
    int nA = blockIdx.x * 8 + w * 2;     // grid exact: 6250*8 = 50000
    int nB = nA + 1;
    int hd = lane >> 4, q = lane & 15;

    int degA = counts[nA]; if (degA > MAXDEG) degA = MAXDEG;
    int degB = counts[nB]; if (degB > MAXDEG) degB = MAXDEG;
    double S = 4.0 * Ssum[0];                       // sent_e tiled over heads
    double zdA = z_dst[nA * N_HEADS + hd];
    double zdB = z_dst[nB * N_HEADS + hd];

    // ---- edge-id gather (both nodes issued before use) ----
    int sA[4], sB[4];
    #pragma unroll
    for (int j = 0; j < 4; ++j) {
        int ei = q + 16 * j;
        sA[j] = (ei < degA) ? srt_padded[nA * MAXDEG + ei] : 0;
        sB[j] = (ei < degB) ? srt_padded[nB * MAXDEG + ei] : 0;
    }
    // ---- z_src scatter-gather + leaky (f64, then round) ----
    float yA[4], yB[4];
    #pragma unroll
    for (int j = 0; j < 4; ++j) {
        int ei = q + 16 * j;
        yA[j] = -INFINITY;
        yB[j] = -INFINITY;
        if (ei < degA) {
            double yy = z_src[sA[j] * N_HEADS + hd] + zdA;
            yy = yy > 0.0 ? yy : 0.01 * yy;
            yA[j] = (float)yy;
        }
        if (ei < degB) {
            double yy = z_src[sB[j] * N_HEADS + hd] + zdB;
            yy = yy > 0.0 ? yy : 0.01 * yy;
            yB[j] = (float)yy;
        }
    }
    // ---- per-head max: two butterfly chains interleaved ----
    float mA = fmaxf(fmaxf(yA[0], yA[1]), fmaxf(yA[2], yA[3]));
    float mB = fmaxf(fmaxf(yB[0], yB[1]), fmaxf(yB[2], yB[3]));
    #pragma unroll
    for (int k = 1; k <= 8; k <<= 1) {
        mA = fmaxf(mA, __shfl_xor(mA, k, 64));
        mB = fmaxf(mB, __shfl_xor(mB, k, 64));
    }
    // ---- exp + denominator (same expression order as R21) ----
    float evA[4], evB[4];
    float dA = 0.f, dB = 0.f;
    #pragma unroll
    for (int j = 0; j < 4; ++j) {
        evA[j] = (yA[j] == -INFINITY) ? 0.f
               : __expf((float)(S * ((double)yA[j] - (double)mA)));
        dA += evA[j];
        evB[j] = (yB[j] == -INFINITY) ? 0.f
               : __expf((float)(S * ((double)yB[j] - (double)mB)));
        dB += evB[j];
    }
    #pragma unroll
    for (int k = 1; k <= 8; k <<= 1) {
        dA += __shfl_xor(dA, k, 64);
        dB += __shfl_xor(dB, k, 64);
    }
    // ---- ballot-compressed accumulate, node A then node B (order preserved) ----
    float accA = 0.f;
    #pragma unroll
    for (int j = 0; j < 4; ++j) {
        unsigned long long mk = __ballot(evA[j] != 0.f);
        unsigned um = (unsigned)((mk | (mk >> 16) | (mk >> 32) | (mk >> 48)) & 0xFFFFull);
        while (um) {
            int qq = __builtin_ctz(um);
            um &= um - 1;
            int src = (lane & 48) | qq;                 // own head's copy
            float evv = __shfl(evA[j], src, 64);
            int sj = __shfl(sA[j], src, 64);
            if (evv != 0.f)
                accA = fmaf(evv, h[sj * HID + lane], accA);
        }
    }
    float accB = 0.f;
    #pragma unroll
    for (int j = 0; j < 4; ++j) {
        unsigned long long mk = __ballot(evB[j] != 0.f);
        unsigned um = (unsigned)((mk | (mk >> 16) | (mk >> 32) | (mk >> 48)) & 0xFFFFull);
        while (um) {
            int qq = __builtin_ctz(um);
            um &= um - 1;
            int src = (lane & 48) | qq;
            float evv = __shfl(evB[j], src, 64);
            int sj = __shfl(sB[j], src, 64);
            if (evv != 0.f)
                accB = fmaf(evv, h[sj * HID + lane], accB);
        }
    }
    float rA = (dA > 0.f) ? accA / dA : 0.f;
    float rB = (dB > 0.f) ? accB / dB : 0.f;
    out[nA * HID + lane] = rA > 0.f ? rA : 0.01f * rA;
    out[nB * HID + lane] = rB > 0.f ? rB : 0.01f * rB;
}

static inline char* ws_take(char*& p, size_t bytes) {
    char* cur = p;
    p += (bytes + 255) & ~(size_t)255;   // keep every buffer 256B-aligned
    return cur;
}

extern "C" void kernel_launch(void* const* d_in, const int* in_sizes, int n_in,
                              void* d_out, int out_size, void* d_ws, size_t ws_size,
                              hipStream_t stream) {
    const float* nodes     = (const float*)d_in[0];
    const float* edges     = (const float*)d_in[1];
    const int*   senders   = (const int*)d_in[2];
    const int*   receivers = (const int*)d_in[3];
    const float* W         = (const float*)d_in[4];
    const float* b         = (const float*)d_in[5];
    const float* attn_W    = (const float*)d_in[6];
    const float* attn_b    = (const float*)d_in[7];
    float* out = (float*)d_out;

    char* p = (char*)d_ws;
    float*  h          = (float*)ws_take(p, sizeof(float) * N_NODES * HID);
    double* z_src      = (double*)ws_take(p, sizeof(double) * N_NODES * N_HEADS);
    double* z_dst      = (double*)ws_take(p, sizeof(double) * N_NODES * N_HEADS);
    int*    counts     = (int*)ws_take(p, sizeof(int) * N_NODES);   // contiguous with
    char*   zpad       = ws_take(p, 256);                           // Ssum: one memset
    double* Ssum       = (double*)zpad;
    int*    srt_padded = (int*)ws_take(p, sizeof(int) * (size_t)N_NODES * MAXDEG);

    // counts (256B-rounded) + the Ssum pad in one memset; srt_padded needs no init
    hipMemsetAsync(counts, 0, ((sizeof(int) * N_NODES + 255) & ~(size_t)255) + 256, stream);

    gemm_hist<<<HBLK + 2 * GEMM_BLK, 256, 0, stream>>>(
        nodes, W, b, attn_W, attn_b, edges, h, z_src, z_dst,
        senders, receivers, counts, srt_padded, Ssum);
    node_fused<<<(N_NODES + 7) / 8, 256, 0, stream>>>(
        h, z_src, z_dst, srt_padded, counts, Ssum, out);
}

// Round 16
// 153.075 us; speedup vs baseline: 1.1885x; 1.1061x over previous
//
#include <hip/hip_runtime.h>
#include <math.h>

#define N_NODES 50000
#define N_EDGES 800000
#define IN_DIM 128
#define OUT_DIM 16
#define N_HEADS 4
#define HID 64            // N_HEADS*OUT_DIM
#define AW_COLS 33        // 2*OUT_DIM+1
#define GN 16             // nodes per tile; 3125*16 = 50000 exact
#define GEMM_BLK ((N_NODES + GN - 1) / GN)             // 3125 tiles, x2 halves
#define HE 16             // edges per thread (hist) -- serial chain form: best of 3 measured
#define HBLK ((N_EDGES + 256 * HE - 1) / (256 * HE))   // 196
#define MAXDEG 64         // padded bucket width; deg~Poisson(16), max~35 (12 sigma margin)

// R37 = EXACT R33 restore (session best: 153.5us, absmax 0.015625).
// Hist ledger CLOSED (R34-R36): serial HE=16 fused = 65us dispatch (best);
// HE=2 flood = 90us (scheduler flooded with latency blocks); ILP-8 burst =
// 75us (L2 atomic congestion competes with gemm staging in the overlap).
// The serial chain is the politest co-tenant -- don't touch hist again.
// Phase map (R34 decomposition): hist ~50us@6%occ / gemm_only <48 /
// node_fused <48 / ~40us launch+overhead constant. All pipes >=65% idle
// everywhere: the floor is dependent-memory-latency, not BW/compute.
// Ledger: R33 f32 GEMM kept (absmax identical to f64 -- near-one-hot softmax
// margins tolerate f32 h). R31 output-split kept (LDS 24576, 6 blk/CU).
// R29 f64 MFMA SHELVED (wrong lane mapping, 2 failures). R27 W-from-global
// loses (line-divergent wq). R26 launch_bounds-beyond-VGPR-need spills.
// R24 more-waves-same-traffic loses. R23 dense accumulate loses.
// R21-R31: 7 gemm structures x 2 dtypes all 62-84us -- structural floor.

// LDS plan: phase1 sWh 16KB @0 + sN 8KB @16384 = 24576 B.
// phase2 overlay: scrF 9216 B @0, h_lds 2048 B @9216.
#define SMEM_DOUBLES 3072                  // 24576 B
#define SCR_OFF_F 2304                     // floats; h_lds at byte 9216

__global__ __launch_bounds__(256, 4) void gemm_hist(
    const float* __restrict__ nodes, const float* __restrict__ W,
    const float* __restrict__ b, const float* __restrict__ attn_W,
    const float* __restrict__ attn_b, const float* __restrict__ edges,
    float* __restrict__ h, double* __restrict__ z_src, double* __restrict__ z_dst,
    const int* __restrict__ senders, const int* __restrict__ receivers,
    int* __restrict__ counts, int* __restrict__ srt_padded,
    double* __restrict__ Ssum) {
    __shared__ double smem_d[SMEM_DOUBLES];    // 24576 B, multi-phase overlay
    float* sWh = (float*)smem_d;               // 16 KB: 32 W rows, rotated
    float* sN = (float*)(smem_d + 2048);       // 8 KB @byte 16384, rotated
    int t = threadIdx.x;

    if (blockIdx.x < HBLK) {
        // ---- hist + direct bucket-scatter (serial chain, R17 form) ----
        double* red = smem_d;
        int base = blockIdx.x * 256 * HE + t;
        double sp = 0.0;
        #pragma unroll
        for (int j = 0; j < HE; ++j) {
            int e = base + j * 256;
            if (e < N_EDGES) {
                int r = receivers[e];
                int rank = atomicAdd(&counts[r], 1);            // 0..deg-1
                if (rank < MAXDEG)
                    srt_padded[r * MAXDEG + rank] = senders[e];
                sp += (double)edges[senders[e]];
            }
        }
        red[t] = sp;
        __syncthreads();
        for (int off = 128; off > 0; off >>= 1) {
            if (t < off) red[t] += red[t + off];
            __syncthreads();
        }
        if (t == 0) atomicAdd(Ssum, red[0]);
    } else {
        // ---- gemm: one 32-out half of a 16-node tile; 4-way k-split; f32 ----
        int bidp = blockIdx.x - HBLK;          // [0, 6250)
        int hhalf = bidp & 1;                  // output half: 0 -> outs[0,32), 1 -> [32,64)
        int node0 = (bidp >> 1) * GN;

        for (int i4 = t; i4 < 32 * IN_DIM / 4; i4 += 256) {    // 1024 quads
            int o = i4 >> 5, kq = i4 & 31;     // o = local out row [0,32)
            float4 v = ((const float4*)W)[(hhalf * 32 + o) * (IN_DIM / 4) + kq];
            *(float4*)&sWh[o * IN_DIM + (((kq + o) & 31) << 2)] = v;
        }
        for (int i4 = t; i4 < GN * IN_DIM / 4; i4 += 256) {    // 512 quads, rotated
            int ln = i4 >> 5, kq = i4 & 31;
            float4 v = ((const float4*)nodes)[(long long)(node0 + ln) * (IN_DIM / 4) + kq];
            *(float4*)&sN[ln * IN_DIM + (((kq + ln) & 31) << 2)] = v;
        }
        __syncthreads();                   // barrier 1

        int w = t >> 6, l = t & 63;
        int og = l & 15;                   // local outs og + 16j, j=0..1
        int ng = l >> 4;                   // nodes   ng + 4i,  i=0..3
        int kbase = w * 8;                 // this wave's kq range [kbase, kbase+8)

        float acc[2][4];                   // [j][i] -- f32 accumulate
        #pragma unroll
        for (int j = 0; j < 2; ++j)
            #pragma unroll
            for (int i = 0; i < 4; ++i) acc[j][i] = 0.f;

        #pragma unroll
        for (int s = 0; s < 8; ++s) {
            int kq = kbase + s;
            float4 wq[2], xq[4];
            #pragma unroll
            for (int j = 0; j < 2; ++j) {
                int o = og + 16 * j;
                wq[j] = *(const float4*)&sWh[o * IN_DIM + (((kq + o) & 31) << 2)];
            }
            #pragma unroll
            for (int i = 0; i < 4; ++i) {
                int n = ng + 4 * i;
                xq[i] = *(const float4*)&sN[n * IN_DIM + (((kq + n) & 31) << 2)];
            }
            #pragma unroll
            for (int j = 0; j < 2; ++j) {
                #pragma unroll
                for (int i = 0; i < 4; ++i) {
                    acc[j][i] = fmaf(wq[j].x, xq[i].x, acc[j][i]);
                    acc[j][i] = fmaf(wq[j].y, xq[i].y, acc[j][i]);
                    acc[j][i] = fmaf(wq[j].z, xq[i].z, acc[j][i]);
                    acc[j][i] = fmaf(wq[j].w, xq[i].w, acc[j][i]);
                }
            }
        }
        __syncthreads();                   // barrier 2: sWh/sN reads done

        // ---- k-reduction (f32): all waves dump; waves 0,1 sum quad j=w ----
        float* scrF = (float*)smem_d;      // overlays dead staging; 9216 B
        float* h_lds = (float*)smem_d + SCR_OFF_F;     // 2 KB @byte 9216
        {
            float* dst = &scrF[(w * 64 + l) * 9];
            #pragma unroll
            for (int j = 0; j < 2; ++j)
                #pragma unroll
                for (int i = 0; i < 4; ++i) dst[j * 4 + i] = acc[j][i];
        }
        __syncthreads();                   // barrier 3
        if (w < 2) {
            int jw = w;                    // finalize local outs og + 16w
            #pragma unroll
            for (int i = 0; i < 4; ++i) {
                float sum = b[hhalf * 32 + og + 16 * jw];
                sum += scrF[(0 * 64 + l) * 9 + jw * 4 + i];   // k[0,32)
                sum += scrF[(1 * 64 + l) * 9 + jw * 4 + i];   // k[32,64)
                sum += scrF[(2 * 64 + l) * 9 + jw * 4 + i];   // k[64,96)
                sum += scrF[(3 * 64 + l) * 9 + jw * 4 + i];   // k[96,128)
                h_lds[(ng + 4 * i) * 32 + og + 16 * jw] = sum;
            }
        }
        __syncthreads();                   // barrier 4

        // ---- epilogue: heads {hhalf*2, hhalf*2+1}; f64 chains ----
        int half = l >> 5;
        int o2 = l & 31;                   // local out column [0,32)
        int nwbase = w * 4 + half * 2;
        int hdl = o2 >> 4, d = o2 & 15;
        int hdg = hhalf * 2 + hdl;         // global head
        double aw0 = (double)attn_W[hdg * AW_COLS + d];            // a_src
        double aw1 = (double)attn_W[hdg * AW_COLS + OUT_DIM + d];  // a_dst
        double wE = (double)attn_W[hdg * AW_COLS + 2 * OUT_DIM];
        double bbv = (double)attn_b[hdg];
        #pragma unroll
        for (int j = 0; j < 2; ++j) {
            int nl = nwbase + j;
            int n = node0 + nl;            // always < 50000 (exact tiling)
            float hf = h_lds[nl * 32 + o2];
            double c0 = (double)hf * aw0;
            double c1 = (double)hf * aw1;
            #pragma unroll
            for (int k = 1; k <= 8; k <<= 1) {
                c0 += __shfl_xor(c0, k, 64);
                c1 += __shfl_xor(c1, k, 64);
            }
            if (d == 0) {
                double se = (double)edges[n];
                z_src[n * N_HEADS + hdg] = c0 + se * wE;
                z_dst[n * N_HEADS + hdg] = c1 + bbv;
            }
        }
        // h write: this block's half-columns for 16 nodes (128 float4)
        if (t < 128) {
            int node = t >> 3, c = t & 7;
            ((float4*)h)[(long long)(node0 + node) * (HID / 4) + hhalf * 8 + c] =
                ((const float4*)h_lds)[node * 8 + c];
        }
    }
}

// R22 form (best known, FROZEN). TWO nodes per wave, phases pairwise
// interleaved; near-one-hot softmax -> ballot loop does ~1-4 gathers/node
// (R23's dense rewrite did 16x traffic, +12us -- don't retry).
__global__ __launch_bounds__(256, 8) void node_fused(
    const float* __restrict__ h, const double* __restrict__ z_src,
    const double* __restrict__ z_dst,
    const int* __restrict__ srt_padded, const int* __restrict__ counts,
    const double* __restrict__ Ssum, float* __restrict__ out) {
    int w = threadIdx.x >> 6;
    int lane = threadIdx.x & 63;
    int nA = blockIdx.x * 8 + w * 2;     // grid exact: 6250*8 = 50000
    int nB = nA + 1;
    int hd = lane >> 4, q = lane & 15;

    int degA = counts[nA]; if (degA > MAXDEG) degA = MAXDEG;
    int degB = counts[nB]; if (degB > MAXDEG) degB = MAXDEG;
    double S = 4.0 * Ssum[0];                       // sent_e tiled over heads
    double zdA = z_dst[nA * N_HEADS + hd];
    double zdB = z_dst[nB * N_HEADS + hd];

    // ---- edge-id gather (both nodes issued before use) ----
    int sA[4], sB[4];
    #pragma unroll
    for (int j = 0; j < 4; ++j) {
        int ei = q + 16 * j;
        sA[j] = (ei < degA) ? srt_padded[nA * MAXDEG + ei] : 0;
        sB[j] = (ei < degB) ? srt_padded[nB * MAXDEG + ei] : 0;
    }
    // ---- z_src scatter-gather + leaky (f64, then round) ----
    float yA[4], yB[4];
    #pragma unroll
    for (int j = 0; j < 4; ++j) {
        int ei = q + 16 * j;
        yA[j] = -INFINITY;
        yB[j] = -INFINITY;
        if (ei < degA) {
            double yy = z_src[sA[j] * N_HEADS + hd] + zdA;
            yy = yy > 0.0 ? yy : 0.01 * yy;
            yA[j] = (float)yy;
        }
        if (ei < degB) {
            double yy = z_src[sB[j] * N_HEADS + hd] + zdB;
            yy = yy > 0.0 ? yy : 0.01 * yy;
            yB[j] = (float)yy;
        }
    }
    // ---- per-head max: two butterfly chains interleaved ----
    float mA = fmaxf(fmaxf(yA[0], yA[1]), fmaxf(yA[2], yA[3]));
    float mB = fmaxf(fmaxf(yB[0], yB[1]), fmaxf(yB[2], yB[3]));
    #pragma unroll
    for (int k = 1; k <= 8; k <<= 1) {
        mA = fmaxf(mA, __shfl_xor(mA, k, 64));
        mB = fmaxf(mB, __shfl_xor(mB, k, 64));
    }
    // ---- exp + denominator (same expression order as R21) ----
    float evA[4], evB[4];
    float dA = 0.f, dB = 0.f;
    #pragma unroll
    for (int j = 0; j < 4; ++j) {
        evA[j] = (yA[j] == -INFINITY) ? 0.f
               : __expf((float)(S * ((double)yA[j] - (double)mA)));
        dA += evA[j];
        evB[j] = (yB[j] == -INFINITY) ? 0.f
               : __expf((float)(S * ((double)yB[j] - (double)mB)));
        dB += evB[j];
    }
    #pragma unroll
    for (int k = 1; k <= 8; k <<= 1) {
        dA += __shfl_xor(dA, k, 64);
        dB += __shfl_xor(dB, k, 64);
    }
    // ---- ballot-compressed accumulate, node A then node B (order preserved) ----
    float accA = 0.f;
    #pragma unroll
    for (int j = 0; j < 4; ++j) {
        unsigned long long mk = __ballot(evA[j] != 0.f);
        unsigned um = (unsigned)((mk | (mk >> 16) | (mk >> 32) | (mk >> 48)) & 0xFFFFull);
        while (um) {
            int qq = __builtin_ctz(um);
            um &= um - 1;
            int src = (lane & 48) | qq;                 // own head's copy
            float evv = __shfl(evA[j], src, 64);
            int sj = __shfl(sA[j], src, 64);
            if (evv != 0.f)
                accA = fmaf(evv, h[sj * HID + lane], accA);
        }
    }
    float accB = 0.f;
    #pragma unroll
    for (int j = 0; j < 4; ++j) {
        unsigned long long mk = __ballot(evB[j] != 0.f);
        unsigned um = (unsigned)((mk | (mk >> 16) | (mk >> 32) | (mk >> 48)) & 0xFFFFull);
        while (um) {
            int qq = __builtin_ctz(um);
            um &= um - 1;
            int src = (lane & 48) | qq;
            float evv = __shfl(evB[j], src, 64);
            int sj = __shfl(sB[j], src, 64);
            if (evv != 0.f)
                accB = fmaf(evv, h[sj * HID + lane], accB);
        }
    }
    float rA = (dA > 0.f) ? accA / dA : 0.f;
    float rB = (dB > 0.f) ? accB / dB : 0.f;
    out[nA * HID + lane] = rA > 0.f ? rA : 0.01f * rA;
    out[nB * HID + lane] = rB > 0.f ? rB : 0.01f * rB;
}

static inline char* ws_take(char*& p, size_t bytes) {
    char* cur = p;
    p += (bytes + 255) & ~(size_t)255;   // keep every buffer 256B-aligned
    return cur;
}

extern "C" void kernel_launch(void* const* d_in, const int* in_sizes, int n_in,
                              void* d_out, int out_size, void* d_ws, size_t ws_size,
                              hipStream_t stream) {
    const float* nodes     = (const float*)d_in[0];
    const float* edges     = (const float*)d_in[1];
    const int*   senders   = (const int*)d_in[2];
    const int*   receivers = (const int*)d_in[3];
    const float* W         = (const float*)d_in[4];
    const float* b         = (const float*)d_in[5];
    const float* attn_W    = (const float*)d_in[6];
    const float* attn_b    = (const float*)d_in[7];
    float* out = (float*)d_out;

    char* p = (char*)d_ws;
    float*  h          = (float*)ws_take(p, sizeof(float) * N_NODES * HID);
    double* z_src      = (double*)ws_take(p, sizeof(double) * N_NODES * N_HEADS);
    double* z_dst      = (double*)ws_take(p, sizeof(double) * N_NODES * N_HEADS);
    int*    counts     = (int*)ws_take(p, sizeof(int) * N_NODES);   // contiguous with
    char*   zpad       = ws_take(p, 256);                           // Ssum: one memset
    double* Ssum       = (double*)zpad;
    int*    srt_padded = (int*)ws_take(p, sizeof(int) * (size_t)N_NODES * MAXDEG);

    // counts (256B-rounded) + the Ssum pad in one memset; srt_padded needs no init
    hipMemsetAsync(counts, 0, ((sizeof(int) * N_NODES + 255) & ~(size_t)255) + 256, stream);

    gemm_hist<<<HBLK + 2 * GEMM_BLK, 256, 0, stream>>>(
        nodes, W, b, attn_W, attn_b, edges, h, z_src, z_dst,
        senders, receivers, counts, srt_padded, Ssum);
    node_fused<<<(N_NODES + 7) / 8, 256, 0, stream>>>(
        h, z_src, z_dst, srt_padded, counts, Ssum, out);
}